// Round 1
// baseline (418.314 us; speedup 1.0000x reference)
//
#include <hip/hip_runtime.h>
#include <math.h>

// QSAR graph-conv pipeline, fully fused: one block per molecule.
// B=4096, A=64, D=6, AF=37, BF=6, H=128, MAX_DEG=6.
// deg==6 atoms produce ZERO from graph_conv (loop d in 0..5 never matches),
// so convs only run for the ~9% of atoms with deg<6 (worklist).

__global__ __launch_bounds__(256, 3) void qsar_fused(
    const float* __restrict__ atoms, const float* __restrict__ bonds,
    const int* __restrict__ edges,
    const float* __restrict__ W1, const float* __restrict__ b1,
    const float* __restrict__ W2, const float* __restrict__ b2,
    const float* __restrict__ Wo, const float* __restrict__ bo,
    const float* __restrict__ Wm1, const float* __restrict__ bm1,
    const float* __restrict__ Wm2, const float* __restrict__ bm2,
    const float* __restrict__ Wm3, const float* __restrict__ bm3,
    float* __restrict__ out)
{
  const int b    = blockIdx.x;
  const int tid  = threadIdx.x;
  const int lane = tid & 63;
  const int wid  = tid >> 6;

  __shared__ float s_x[64 * 128];     // main buffer: x1 -> x1p -> ysum -> x2 -> x2p -> logits -> probs
  __shared__ float s_sa[64 * 38];     // summed atom feats (37 used, pad 38)
  __shared__ float s_bsum[64 * 8];    // bonds.sum(2) (6 used, pad 8)
  __shared__ int   s_edges[64 * 6];
  __shared__ int   s_deg[64];
  __shared__ int   s_work[64];
  __shared__ int   s_nwork;
  __shared__ float s_rsum[64];        // (deg!=0) ? 1/sum(exp) : 0
  __shared__ float s_fp[2 * 128];
  __shared__ float s_h1[64];
  __shared__ float s_h2[32];

  float* s_atoms = s_x;               // [64][38] alias; dead before s_x first written

  // ---------------- P0: stage atoms/edges, bonds-sum, degree, worklist ----------------
  {
    const float* ga = atoms + (size_t)b * (64 * 37);
    for (int i = tid; i < 64 * 37; i += 256) {
      int a = i / 37, k = i - a * 37;
      s_atoms[a * 38 + k] = ga[i];
    }
    const int* ge = edges + (size_t)b * (64 * 6);
    for (int i = tid; i < 64 * 6; i += 256) s_edges[i] = ge[i];
    if (tid == 0) s_nwork = 0;
    const float* gb = bonds + (size_t)b * (64 * 36);
    for (int i = tid; i < 64 * 6; i += 256) {
      int a = i / 6, f = i - a * 6;
      float s = 0.f;
#pragma unroll
      for (int d = 0; d < 6; ++d) s += gb[a * 36 + d * 6 + f];
      s_bsum[a * 8 + f] = s;
    }
  }
  __syncthreads();
  if (tid < 64) {
    int dcnt = 0;
#pragma unroll
    for (int d = 0; d < 6; ++d) dcnt += (s_edges[tid * 6 + d] >= 0) ? 1 : 0;
    s_deg[tid] = dcnt;
    if (dcnt < 6) { int p = atomicAdd(&s_nwork, 1); s_work[p] = tid; }
  }
  __syncthreads();

  // ---------------- P1a: summed atoms (self + valid neighbors), work rows only --------
  for (int i = tid; i < 64 * 37; i += 256) {
    int a = i / 37, k = i - a * 37;
    if (s_deg[a] < 6) {
      float s = s_atoms[a * 38 + k];
#pragma unroll
      for (int d = 0; d < 6; ++d) {
        int e = s_edges[a * 6 + d];
        if (e >= 0) s += s_atoms[e * 38 + k];
      }
      s_sa[a * 38 + k] = s;
    }
  }
  __syncthreads();

  // ---------------- P1b: conv1 -> s_x (deg==6 rows -> 0; work rows per wave) ----------
  {
    for (int i = tid; i < 64 * 128; i += 256) {
      int a = i >> 7;
      if (s_deg[a] == 6) s_x[i] = 0.f;
    }
    const int nw = s_nwork;
    for (int w = wid; w < nw; w += 4) {
      int a = s_work[w];
      int d = s_deg[a];
      const float* wp = W1 + d * (43 * 128);
      float acc0 = b1[d * 128 + lane];
      float acc1 = b1[d * 128 + 64 + lane];
      for (int k = 0; k < 37; ++k) {
        float f = s_sa[a * 38 + k];
        acc0 = fmaf(f, wp[k * 128 + lane], acc0);
        acc1 = fmaf(f, wp[k * 128 + 64 + lane], acc1);
      }
#pragma unroll
      for (int k = 0; k < 6; ++k) {
        float f = s_bsum[a * 8 + k];
        acc0 = fmaf(f, wp[(37 + k) * 128 + lane], acc0);
        acc1 = fmaf(f, wp[(37 + k) * 128 + 64 + lane], acc1);
      }
      // wave-lockstep: all reads of row a done before these writes
      s_x[a * 128 + lane]      = fmaxf(acc0, 0.f);
      s_x[a * 128 + 64 + lane] = fmaxf(acc1, 0.f);
    }
  }
  __syncthreads();

  // ---------------- P2: pool1 in place (max over self + valid neighbors) --------------
  {
    float pv[32];
#pragma unroll
    for (int j = 0; j < 32; ++j) {
      int i = tid + j * 256;
      int a = i >> 7, c = i & 127;
      float m = s_x[i];
#pragma unroll
      for (int d = 0; d < 6; ++d) {
        int e = s_edges[a * 6 + d];
        if (e >= 0) m = fmaxf(m, s_x[e * 128 + c]);
      }
      pv[j] = m;
    }
    __syncthreads();
#pragma unroll
    for (int j = 0; j < 32; ++j) s_x[tid + j * 256] = pv[j];
  }
  __syncthreads();

  // ---------------- P2b: neighbor-sum of pooled, in place, work rows only -------------
  {
    float pv[32];
#pragma unroll
    for (int j = 0; j < 32; ++j) {
      int i = tid + j * 256;
      int a = i >> 7, c = i & 127;
      if (s_deg[a] < 6) {
        float s = s_x[i];
#pragma unroll
        for (int d = 0; d < 6; ++d) {
          int e = s_edges[a * 6 + d];
          if (e >= 0) s += s_x[e * 128 + c];
        }
        pv[j] = s;
      }
    }
    __syncthreads();
#pragma unroll
    for (int j = 0; j < 32; ++j) {
      int i = tid + j * 256;
      int a = i >> 7;
      if (s_deg[a] < 6) s_x[i] = pv[j];
    }
  }
  __syncthreads();

  // ---------------- P3: conv2 in place (reads own row only) ---------------------------
  {
    for (int i = tid; i < 64 * 128; i += 256) {
      int a = i >> 7;
      if (s_deg[a] == 6) s_x[i] = 0.f;   // disjoint from work rows: safe concurrently
    }
    const int nw = s_nwork;
    for (int w = wid; w < nw; w += 4) {
      int a = s_work[w];
      int d = s_deg[a];
      const float* wp = W2 + d * (134 * 128);
      float acc0 = b2[d * 128 + lane];
      float acc1 = b2[d * 128 + 64 + lane];
      for (int k = 0; k < 128; ++k) {
        float f = s_x[a * 128 + k];
        acc0 = fmaf(f, wp[k * 128 + lane], acc0);
        acc1 = fmaf(f, wp[k * 128 + 64 + lane], acc1);
      }
#pragma unroll
      for (int k = 0; k < 6; ++k) {
        float f = s_bsum[a * 8 + k];
        acc0 = fmaf(f, wp[(128 + k) * 128 + lane], acc0);
        acc1 = fmaf(f, wp[(128 + k) * 128 + 64 + lane], acc1);
      }
      s_x[a * 128 + lane]      = fmaxf(acc0, 0.f);
      s_x[a * 128 + 64 + lane] = fmaxf(acc1, 0.f);
    }
  }
  __syncthreads();

  // ---------------- P4: pool2 in place ------------------------------------------------
  {
    float pv[32];
#pragma unroll
    for (int j = 0; j < 32; ++j) {
      int i = tid + j * 256;
      int a = i >> 7, c = i & 127;
      float m = s_x[i];
#pragma unroll
      for (int d = 0; d < 6; ++d) {
        int e = s_edges[a * 6 + d];
        if (e >= 0) m = fmaxf(m, s_x[e * 128 + c]);
      }
      pv[j] = m;
    }
    __syncthreads();
#pragma unroll
    for (int j = 0; j < 32; ++j) s_x[tid + j * 256] = pv[j];
  }
  __syncthreads();

  // ---------------- P5: graph_output logits GEMM (dense 64x134x128) -------------------
  {
    const int cg = tid & 31, ag = tid >> 5;
    const int c0 = cg * 4, a0 = ag * 8;
    float acc[8][4];
    const float4 bo4 = *reinterpret_cast<const float4*>(bo + c0);
#pragma unroll
    for (int i2 = 0; i2 < 8; ++i2) {
      acc[i2][0] = bo4.x; acc[i2][1] = bo4.y; acc[i2][2] = bo4.z; acc[i2][3] = bo4.w;
    }
#pragma unroll 4
    for (int k = 0; k < 128; ++k) {
      const float4 w4 = *reinterpret_cast<const float4*>(Wo + k * 128 + c0);
#pragma unroll
      for (int i2 = 0; i2 < 8; ++i2) {
        const float f = s_x[(a0 + i2) * 128 + k];   // wave-broadcast read
        acc[i2][0] = fmaf(f, w4.x, acc[i2][0]);
        acc[i2][1] = fmaf(f, w4.y, acc[i2][1]);
        acc[i2][2] = fmaf(f, w4.z, acc[i2][2]);
        acc[i2][3] = fmaf(f, w4.w, acc[i2][3]);
      }
    }
#pragma unroll
    for (int k = 0; k < 6; ++k) {
      const float4 w4 = *reinterpret_cast<const float4*>(Wo + (128 + k) * 128 + c0);
#pragma unroll
      for (int i2 = 0; i2 < 8; ++i2) {
        const float f = s_bsum[(a0 + i2) * 8 + k];
        acc[i2][0] = fmaf(f, w4.x, acc[i2][0]);
        acc[i2][1] = fmaf(f, w4.y, acc[i2][1]);
        acc[i2][2] = fmaf(f, w4.z, acc[i2][2]);
        acc[i2][3] = fmaf(f, w4.w, acc[i2][3]);
      }
    }
    __syncthreads();  // all reads of x2p done before logits overwrite
#pragma unroll
    for (int i2 = 0; i2 < 8; ++i2) {
      *reinterpret_cast<float4*>(&s_x[(a0 + i2) * 128 + c0]) =
          make_float4(acc[i2][0], acc[i2][1], acc[i2][2], acc[i2][3]);
    }
  }
  __syncthreads();

  // ---------------- P6: per-atom softmax over 128 (in place), 4 lanes/atom ------------
  {
    const int a = tid >> 2, q = tid & 3;
    const int base = a * 128 + q * 32;
    float mx = -3.0e38f;
    for (int j = 0; j < 32; ++j) {
      int jj = (j + tid) & 31;                      // swizzle: conflict-free banks
      mx = fmaxf(mx, s_x[base + jj]);
    }
    mx = fmaxf(mx, __shfl_xor(mx, 1));
    mx = fmaxf(mx, __shfl_xor(mx, 2));
    float sm = 0.f;
    for (int j = 0; j < 32; ++j) {
      int jj = (j + tid) & 31;
      float e = __expf(s_x[base + jj] - mx);
      sm += e;
      s_x[base + jj] = e;                           // own segment only: no race
    }
    sm += __shfl_xor(sm, 1);
    sm += __shfl_xor(sm, 2);
    if (q == 0) s_rsum[a] = (s_deg[a] != 0) ? (1.f / sm) : 0.f;
  }
  __syncthreads();

  // ---------------- P7: fingerprint fp[c] = sum_a probs[a][c] -------------------------
  {
    const int c = tid & 127, half = tid >> 7;
    float s = 0.f;
    for (int a2 = half * 32; a2 < half * 32 + 32; ++a2)
      s = fmaf(s_x[a2 * 128 + c], s_rsum[a2], s);
    s_fp[half * 128 + c] = s;
  }
  __syncthreads();
  if (tid < 128) s_fp[tid] += s_fp[128 + tid];
  __syncthreads();

  // ---------------- P8: MLP head ------------------------------------------------------
  if (tid < 64) {
    float acc = bm1[tid];
    for (int k = 0; k < 128; ++k) acc = fmaf(s_fp[k], Wm1[k * 64 + tid], acc);
    s_h1[tid] = fmaxf(acc, 0.f);
  }
  __syncthreads();
  if (tid < 32) {
    float acc = bm2[tid];
    for (int k = 0; k < 64; ++k) acc = fmaf(s_h1[k], Wm2[k * 32 + tid], acc);
    s_h2[tid] = fmaxf(acc, 0.f);
  }
  __syncthreads();
  if (tid < 64) {
    float p = (tid < 32) ? s_h2[tid] * Wm3[tid] : 0.f;
#pragma unroll
    for (int off = 32; off > 0; off >>= 1) p += __shfl_xor(p, off);
    if (tid == 0) out[b] = p + bm3[0];
  }
}

extern "C" void kernel_launch(void* const* d_in, const int* in_sizes, int n_in,
                              void* d_out, int out_size, void* d_ws, size_t ws_size,
                              hipStream_t stream) {
  const float* atoms = (const float*)d_in[0];
  const float* bonds = (const float*)d_in[1];
  const int*   edges = (const int*)d_in[2];
  const float* W1  = (const float*)d_in[3];
  const float* b1  = (const float*)d_in[4];
  const float* W2  = (const float*)d_in[5];
  const float* b2  = (const float*)d_in[6];
  const float* Wo  = (const float*)d_in[7];
  const float* bo  = (const float*)d_in[8];
  const float* Wm1 = (const float*)d_in[9];
  const float* bm1 = (const float*)d_in[10];
  const float* Wm2 = (const float*)d_in[11];
  const float* bm2 = (const float*)d_in[12];
  const float* Wm3 = (const float*)d_in[13];
  const float* bm3 = (const float*)d_in[14];
  float* out = (float*)d_out;

  const int B = out_size;  // 4096 molecules
  qsar_fused<<<dim3(B), dim3(256), 0, stream>>>(
      atoms, bonds, edges, W1, b1, W2, b2, Wo, bo,
      Wm1, bm1, Wm2, bm2, Wm3, bm3, out);
}